// Round 8
// baseline (447.933 us; speedup 1.0000x reference)
//
#include <hip/hip_runtime.h>
#include <hip/hip_bf16.h>
#include <math.h>

typedef unsigned short u16;
typedef __attribute__((ext_vector_type(8))) short bf16x8;
typedef __attribute__((ext_vector_type(4))) short bf16x4;
typedef __attribute__((ext_vector_type(4))) float f32x4;

namespace {

constexpr int BS = 2;
constexpr int S = 2048;
constexpr int D = 2048;
constexpr int DOWN = 512;
constexpr int UP = 1024;
constexpr int H = 16;
constexpr int RD = 32;
constexpr int VD = 64;
constexpr int QKD = 96;
constexpr int M = BS * S;        // 4096
constexpr int N1 = 1152;         // [Wdkv|Wdq|Wkr] padded 1056->9*128
constexpr int N2 = 2048;         // [Wuk|Wuv]
constexpr int N3 = 1536;         // [Wuq|Wqr]

__device__ __forceinline__ float b2f(u16 u) {
  unsigned int x = ((unsigned int)u) << 16;
  return __uint_as_float(x);
}
__device__ __forceinline__ u16 f2b(float f) {
  unsigned int u = __float_as_uint(f);
  u += 0x7fff + ((u >> 16) & 1);  // RNE
  return (u16)(u >> 16);
}
__device__ __forceinline__ void store_out(float* p, float v) { *p = v; }
__device__ __forceinline__ void store_out(u16* p, float v) { *p = f2b(v); }

__device__ __forceinline__ void async16(const u16* g, u16* lds) {
  __builtin_amdgcn_global_load_lds(
      (const __attribute__((address_space(1))) unsigned int*)g,
      (__attribute__((address_space(3))) unsigned int*)lds, 16, 0, 0);
}

__device__ __forceinline__ float exp2_fast(float x) {
#if __has_builtin(__builtin_amdgcn_exp2f)
  return __builtin_amdgcn_exp2f(x);
#else
  float r;
  asm("v_exp_f32 %0, %1" : "=v"(r) : "v"(x));
  return r;
#endif
}

__device__ __forceinline__ bf16x4 pack4(float a, float b, float c, float d) {
  union { __hip_bfloat162 h2[2]; bf16x4 v; } u;
  u.h2[0] = __float22bfloat162_rn(make_float2(a, b));
  u.h2[1] = __float22bfloat162_rn(make_float2(c, d));
  return u.v;
}

__device__ __forceinline__ f32x4 mfma32(bf16x8 a, bf16x8 b, f32x4 c) {
  return __builtin_amdgcn_mfma_f32_16x16x32_bf16(a, b, c, 0, 0, 0);
}
__device__ __forceinline__ f32x4 mfma16(bf16x4 a, bf16x4 b, f32x4 c) {
#if __has_builtin(__builtin_amdgcn_mfma_f32_16x16x16_bf16)
  return __builtin_amdgcn_mfma_f32_16x16x16_bf16(a, b, c, 0, 0, 0);
#elif __has_builtin(__builtin_amdgcn_mfma_f32_16x16x16bf16_1k)
  return __builtin_amdgcn_mfma_f32_16x16x16bf16_1k(a, b, c, 0, 0, 0);
#else
  f32x4 d;
  asm("v_mfma_f32_16x16x16_bf16 %0, %1, %2, %3"
      : "=v"(d) : "v"(a), "v"(b), "v"(c));
  return d;
#endif
}

// ---------------- fused prep: all casts + bias concats + rope tables -------
__global__ __launch_bounds__(256) void prep_kernel(
    const float* __restrict__ h, const float* __restrict__ Wdkv,
    const float* __restrict__ Wdq, const float* __restrict__ Wkr,
    const float* __restrict__ Wuk, const float* __restrict__ Wuv,
    const float* __restrict__ Wuq, const float* __restrict__ Wqr,
    const float* __restrict__ Wfc, const float* __restrict__ bdkv,
    const float* __restrict__ bdq, const float* __restrict__ bkr,
    const float* __restrict__ buk, const float* __restrict__ buv,
    const float* __restrict__ buq, const float* __restrict__ bqr,
    u16* __restrict__ hb, u16* __restrict__ Wcat1, u16* __restrict__ Wcat2,
    u16* __restrict__ Wcat3, u16* __restrict__ Wfcb,
    float* __restrict__ bcat1, float* __restrict__ bcat2,
    float* __restrict__ bcat3, float* __restrict__ ct, float* __restrict__ st) {
  const long i = (long)blockIdx.x * 256 + threadIdx.x;
  if (i >= 3630240) return;
  if (i < 3620864) {  // bf16 casts
    const float* src; u16* dst; long off;
    if      (i < 2097152) { src = h;    dst = hb;              off = i; }
    else if (i < 2359296) { src = Wdkv; dst = Wcat1;           off = i - 2097152; }
    else if (i < 2621440) { src = Wdq;  dst = Wcat1 + 1048576; off = i - 2359296; }
    else if (i < 2637824) { src = Wkr;  dst = Wcat1 + 2097152; off = i - 2621440; }
    else if (i < 2768896) { src = Wuk;  dst = Wcat2;           off = i - 2637824; }
    else if (i < 2899968) { src = Wuv;  dst = Wcat2 + 524288;  off = i - 2768896; }
    else if (i < 3031040) { src = Wuq;  dst = Wcat3;           off = i - 2899968; }
    else if (i < 3096576) { src = Wqr;  dst = Wcat3 + 524288;  off = i - 3031040; }
    else                  { src = Wfc;  dst = Wfcb;            off = i - 3096576; }
    float4 v = ((const float4*)src)[off];
    ushort4 o;
    o.x = f2b(v.x); o.y = f2b(v.y); o.z = f2b(v.z); o.w = f2b(v.w);
    ((ushort4*)dst)[off] = o;
  } else if (i < 3622048) {  // bias concat
    long j0 = (i - 3620864) * 4;
#pragma unroll
    for (int e = 0; e < 4; ++e) {
      long j = j0 + e;
      if (j < N1) {
        float v = 0.f;
        if (j < 512) v = bdkv[j];
        else if (j < 1024) v = bdq[j - 512];
        else if (j < 1056) v = bkr[j - 1024];
        bcat1[j] = v;
      } else if (j < N1 + N2) {
        long jj = j - N1;
        bcat2[jj] = (jj < 1024) ? buk[jj] : buv[jj - 1024];
      } else {
        long jj = j - N1 - N2;
        bcat3[jj] = (jj < 1024) ? buq[jj] : bqr[jj - 1024];
      }
    }
  } else {  // rope tables
    long k0 = (i - 3622048) * 4;
#pragma unroll
    for (int e = 0; e < 4; ++e) {
      long k = k0 + e;
      int s = (int)(k >> 4), r = (int)(k & 15);
      float f = powf(10000.f, -(float)r / 16.f);
      float th = (float)s * f;
      ct[k] = cosf(th);
      st[k] = sinf(th);
    }
  }
}

// ---------------- bf16 MFMA GEMM body (async LDS staging, m97 structure) ----
template <int BN, typename OutT>
__device__ __forceinline__ void gemm_body(
    const u16* __restrict__ A, int lda, const u16* __restrict__ W, int ldw,
    const float* __restrict__ bias, OutT* __restrict__ C, int ldc, int K,
    int m0, int n0) {
  constexpr int NFR = BN / 32;
  __shared__ u16 As[128 * 32];
  __shared__ u16 Bs[BN * 32];
  const int t = threadIdx.x;
  const int lane = t & 63, wave = t >> 6;
  const int wm = (wave >> 1) * 64, wn = (wave & 1) * (BN / 2);
  const int lrow = lane & 15, lk = (lane >> 4) * 8;
  const int srow = lane >> 2, scol = (lane & 3) * 8;  // 16 rows per instr
  f32x4 acc[4][NFR] = {};
  for (int k0 = 0; k0 < K; k0 += 32) {
    __syncthreads();
    {
      int r = wave * 32 + srow;
      async16(A + (size_t)(m0 + r) * lda + k0 + scol, As + (wave * 32) * 32);
      async16(A + (size_t)(m0 + r + 16) * lda + k0 + scol,
              As + (wave * 32 + 16) * 32);
    }
    if (BN == 128) {
      int r = wave * 32 + srow;
      async16(W + (size_t)(n0 + r) * ldw + k0 + scol, Bs + (wave * 32) * 32);
      async16(W + (size_t)(n0 + r + 16) * ldw + k0 + scol,
              Bs + (wave * 32 + 16) * 32);
    } else {
      int r = wave * 16 + srow;
      async16(W + (size_t)(n0 + r) * ldw + k0 + scol, Bs + (wave * 16) * 32);
    }
    __syncthreads();
    bf16x8 af[4], bfr[NFR];
#pragma unroll
    for (int i = 0; i < 4; ++i)
      af[i] = *(const bf16x8*)(As + (wm + i * 16 + lrow) * 32 + lk);
#pragma unroll
    for (int i = 0; i < NFR; ++i)
      bfr[i] = *(const bf16x8*)(Bs + (wn + i * 16 + lrow) * 32 + lk);
#pragma unroll
    for (int mi = 0; mi < 4; ++mi)
#pragma unroll
      for (int ni = 0; ni < NFR; ++ni)
        acc[mi][ni] = mfma32(af[mi], bfr[ni], acc[mi][ni]);
  }
#pragma unroll
  for (int mi = 0; mi < 4; ++mi)
#pragma unroll
    for (int ni = 0; ni < NFR; ++ni)
#pragma unroll
      for (int r = 0; r < 4; ++r) {
        int m = m0 + wm + mi * 16 + (lane >> 4) * 4 + r;
        int n = n0 + wn + ni * 16 + lrow;
        store_out(C + (size_t)m * ldc + n, acc[mi][ni][r] + bias[n]);
      }
}

template <int BN, typename OutT>
__global__ __launch_bounds__(256) void gemm_bt_mfma(
    const u16* __restrict__ A, int lda, const u16* __restrict__ W, int ldw,
    const float* __restrict__ bias, OutT* __restrict__ C, int ldc, int K) {
  gemm_body<BN, OutT>(A, lda, W, ldw, bias, C, ldc, K,
                      blockIdx.x * 128, blockIdx.y * BN);
}

// G2 and G3 share M and K — one launch, branch on blockIdx.y.
__global__ __launch_bounds__(256) void gemm_up_fused(
    const u16* __restrict__ C1v, const u16* __restrict__ Wcat2,
    const u16* __restrict__ Wcat3, const float* __restrict__ bcat2,
    const float* __restrict__ bcat3, u16* __restrict__ C2,
    u16* __restrict__ C3) {
  const int by = blockIdx.y;
  const u16* A;
  const u16* W;
  const float* bias;
  u16* C;
  int ldc, n0;
  if (by < 16) {
    A = C1v; W = Wcat2; bias = bcat2; C = C2; ldc = N2; n0 = by * 128;
  } else {
    A = C1v + DOWN; W = Wcat3; bias = bcat3; C = C3; ldc = N3;
    n0 = (by - 16) * 128;
  }
  gemm_body<128, u16>(A, N1, W, DOWN, bias, C, ldc, DOWN,
                      blockIdx.x * 128, n0);
}

// ---------------- bf16 64x64-tile transpose with strides -------------------
__global__ __launch_bounds__(256) void transpose_kernel(
    const u16* __restrict__ in, int ld_in, u16* __restrict__ outT, int ld_out) {
  __shared__ u16 tile[64][72];
  const int m0 = blockIdx.x * 64, n0 = blockIdx.y * 64;
  const int r = threadIdx.x >> 2, c0 = (threadIdx.x & 3) * 16;
  *(bf16x8*)(&tile[r][c0]) =
      *(const bf16x8*)(in + (size_t)(m0 + r) * ld_in + n0 + c0);
  *(bf16x8*)(&tile[r][c0 + 8]) =
      *(const bf16x8*)(in + (size_t)(m0 + r) * ld_in + n0 + c0 + 8);
  __syncthreads();
  bf16x8 o0, o1;
#pragma unroll
  for (int j = 0; j < 8; ++j) {
    o0[j] = (short)tile[c0 + j][r];
    o1[j] = (short)tile[c0 + 8 + j][r];
  }
  *(bf16x8*)(outT + (size_t)(n0 + r) * ld_out + m0 + c0) = o0;
  *(bf16x8*)(outT + (size_t)(n0 + r) * ld_out + m0 + c0 + 8) = o1;
}

// ---------------- fused RoPE packs (Q: z<BS, K: z>=BS) ----------------
__global__ __launch_bounds__(192) void pack_qk_kernel(
    const u16* __restrict__ qc, const u16* __restrict__ qr,  // strides N3
    const u16* __restrict__ kc,  // stride N2
    const u16* __restrict__ kr,  // stride N1
    const float* __restrict__ ct, const float* __restrict__ st,
    u16* __restrict__ Qp, u16* __restrict__ Kp) {
  const int t = threadIdx.x;
  const int sub = (t >= 96) ? 1 : 0;
  const int d = t - sub * 96;
  const int s = blockIdx.x * 2 + sub, h = blockIdx.y;
  const int z = blockIdx.z;
  const float sc = 1.44269504088896f / (sqrtf(128.f) + sqrtf(32.f));
  float val;
  if (z < BS) {  // Q
    const int b = z;
    if (d < 64) {
      val = b2f(qc[(size_t)(b * S + s) * N3 + h * VD + d]);
    } else {
      int r = d - 64;
      const u16* qrow = qr + (size_t)(b * S + s) * N3 + h * RD;
      float x = b2f(qrow[r]), xp = b2f(qrow[r ^ 16]);
      float c = ct[s * 16 + (r & 15)], sn = st[s * 16 + (r & 15)];
      val = (r < 16) ? (x * c - xp * sn) : (x * c + xp * sn);
    }
    Qp[((size_t)(b * H + h) * S + s) * QKD + d] = f2b(val * sc);
  } else {  // K
    const int b = z - BS;
    if (d < 64) {
      val = b2f(kc[(size_t)(b * S + s) * N2 + h * VD + d]);
    } else {
      int r = d - 64;
      const u16* krow = kr + (size_t)(b * S + s) * N1;
      float x = b2f(krow[r]), xp = b2f(krow[r ^ 16]);
      float c = ct[s * 16 + (r & 15)], sn = st[s * 16 + (r & 15)];
      val = (r < 16) ? (x * c - xp * sn) : (x * c + xp * sn);
    }
    Kp[((size_t)(b * H + h) * S + s) * QKD + d] = f2b(val);
  }
}

// ---------------- barrier-free split-K MFMA flash attention ----------------
// One wave per (16-q tile, key-half). Scores S^T via 16x16x32 (A=K, B=Q):
// C-layout (q=lane&15, key=quad*4+r) IS the 16x16x16 PV A-operand ->
// pack4 direct, zero cross-lane remap. K/V fragments load straight from
// global (L1/L2). Two split waves combine O/lsum via LDS with ONE barrier.
// Block pairs tile j with 127-j: constant work per block.
__global__ __launch_bounds__(256) void attn_mfma(
    const u16* __restrict__ Qp, const u16* __restrict__ Kp,
    const u16* __restrict__ Vt, u16* __restrict__ attnb) {
  __shared__ float sO[2][64][17];
  const int t = threadIdx.x, wave = t >> 6, lane = t & 63;
  const int tid = wave >> 1, sp = wave & 1;  // tile-in-block, split
  const int bh = blockIdx.x & 31;
  const int b = bh >> 4, h = bh & 15;
  const int j = blockIdx.x >> 5;  // 0..63
  const int tl = (tid == 0) ? j : (127 - j);
  const int qX = tl * 16;
  const int l15 = lane & 15, quad = lane >> 4;
  const size_t hbo = (size_t)bh * S;

  // Q B-operand fragments: lane holds q=l15, d=c*32+quad*8+0..7
  bf16x8 qf[3];
  {
    const u16* qrow = Qp + (hbo + qX + l15) * QKD + quad * 8;
#pragma unroll
    for (int c = 0; c < 3; ++c) qf[c] = *(const bf16x8*)(qrow + c * 32);
  }
  f32x4 O[4] = {};
  float lsum = 0.f;
  const int kend = qX + 16;
  const int nk32 = (kend + 31) >> 5;
  const int half = nk32 >> 1;
  const int i0 = sp ? half : 0, i1 = sp ? nk32 : half;
  const u16* vbase =
      Vt + ((size_t)(h * VD + l15)) * M + (size_t)b * S + quad * 4;

  for (int it = i0; it < i1; ++it) {
    const int k0 = it * 32;
#pragma unroll
    for (int sub = 0; sub < 2; ++sub) {
      const int kc0 = k0 + (sub << 4);
      if (kc0 >= kend) break;  // wave-uniform
      const u16* kb = Kp + (hbo + kc0 + l15) * QKD + quad * 8;
      f32x4 s = {0.f, 0.f, 0.f, 0.f};
      s = mfma32(*(const bf16x8*)(kb), qf[0], s);
      s = mfma32(*(const bf16x8*)(kb + 32), qf[1], s);
      s = mfma32(*(const bf16x8*)(kb + 64), qf[2], s);
      float e[4];
      if (kc0 == qX) {  // diagonal subtile: position-only causal mask
#pragma unroll
        for (int r = 0; r < 4; ++r) {
          float v = exp2_fast(s[r]);
          e[r] = (quad * 4 + r <= l15) ? v : 0.f;
        }
      } else {
#pragma unroll
        for (int r = 0; r < 4; ++r) e[r] = exp2_fast(s[r]);
      }
      lsum += (e[0] + e[1]) + (e[2] + e[3]);
      bf16x4 pa = pack4(e[0], e[1], e[2], e[3]);
#pragma unroll
      for (int v = 0; v < 4; ++v) {
        bf16x4 vf = *(const bf16x4*)(vbase + (size_t)(v * 16) * M + kc0);
        O[v] = mfma16(pa, vf, O[v]);
      }
    }
  }

  if (sp == 1) {
#pragma unroll
    for (int v = 0; v < 4; ++v)
#pragma unroll
      for (int r = 0; r < 4; ++r) sO[tid][lane][v * 4 + r] = O[v][r];
    sO[tid][lane][16] = lsum;
  }
  __syncthreads();
  if (sp == 0) {
#pragma unroll
    for (int v = 0; v < 4; ++v)
#pragma unroll
      for (int r = 0; r < 4; ++r) O[v][r] += sO[tid][lane][v * 4 + r];
    lsum += sO[tid][lane][16];
    lsum += __shfl_xor(lsum, 16);
    lsum += __shfl_xor(lsum, 32);  // lane now has total for q = l15
    u16* ob = attnb + (size_t)b * S * UP + h * VD;
#pragma unroll
    for (int r = 0; r < 4; ++r) {
      float linv = 1.f / __shfl(lsum, quad * 4 + r);
      size_t row = (size_t)(qX + quad * 4 + r) * UP;
#pragma unroll
      for (int v = 0; v < 4; ++v) ob[row + v * 16 + l15] = f2b(O[v][r] * linv);
    }
  }
}

}  // namespace

extern "C" void kernel_launch(void* const* d_in, const int* in_sizes, int n_in,
                              void* d_out, int out_size, void* d_ws, size_t ws_size,
                              hipStream_t stream) {
  const float* h    = (const float*)d_in[0];
  const float* Wdkv = (const float*)d_in[2];
  const float* bdkv = (const float*)d_in[3];
  const float* Wuk  = (const float*)d_in[4];
  const float* buk  = (const float*)d_in[5];
  const float* Wuv  = (const float*)d_in[6];
  const float* buv  = (const float*)d_in[7];
  const float* Wdq  = (const float*)d_in[8];
  const float* bdq  = (const float*)d_in[9];
  const float* Wuq  = (const float*)d_in[10];
  const float* buq  = (const float*)d_in[11];
  const float* Wqr  = (const float*)d_in[12];
  const float* bqr  = (const float*)d_in[13];
  const float* Wkr  = (const float*)d_in[14];
  const float* bkr  = (const float*)d_in[15];
  const float* Wfc  = (const float*)d_in[16];
  const float* bfc  = (const float*)d_in[17];
  float* out = (float*)d_out;

  // workspace carve-up (u16 units; ~102 MB)
  u16* p = (u16*)d_ws;
  u16* hb    = p; p += (size_t)M * D;
  u16* Wcat1 = p; p += (size_t)N1 * D;       // [Wdkv|Wdq|Wkr|pad]
  u16* Wcat2 = p; p += (size_t)N2 * DOWN;    // [Wuk|Wuv]
  u16* Wcat3 = p; p += (size_t)N3 * DOWN;    // [Wuq|Wqr]
  u16* Wfcb  = p; p += (size_t)D * UP;
  u16* C1    = p; p += (size_t)M * N1;       // ckv|cq|kr
  u16* C2    = p; p += (size_t)M * N2;       // kc|vc
  u16* C3    = p; p += (size_t)M * N3;       // qc|qr
  u16* Qp    = p; p += 6291456;              // [b][h][s][96]
  u16* Kp    = p; p += 6291456;
  u16* Vt    = p; p += (size_t)UP * M;       // [h*64+vd][b*S+s]
  float* bcat1 = (float*)p; p += 2 * N1;
  float* bcat2 = (float*)p; p += 2 * N2;
  float* bcat3 = (float*)p; p += 2 * N3;
  float* ct = (float*)p; p += 2 * S * 16;
  float* st = (float*)p; p += 2 * S * 16;
  u16* attnb = C1;  // C1 dead after pack_qk

  prep_kernel<<<dim3(14181), 256, 0, stream>>>(
      h, Wdkv, Wdq, Wkr, Wuk, Wuv, Wuq, Wqr, Wfc,
      bdkv, bdq, bkr, buk, buv, buq, bqr,
      hb, Wcat1, Wcat2, Wcat3, Wfcb, bcat1, bcat2, bcat3, ct, st);

  // G1: [c_kv | c_q | k_r] = h @ Wcat1^T  (BN=64 -> 576 blocks)
  gemm_bt_mfma<64, u16><<<dim3(M / 128, N1 / 64), 256, 0, stream>>>(
      hb, D, Wcat1, D, bcat1, C1, N1, D);
  // G2+G3 fused: [k_c|v_c] and [q_c|q_r]  (896 blocks)
  gemm_up_fused<<<dim3(M / 128, 28), 256, 0, stream>>>(
      C1, Wcat2, Wcat3, bcat2, bcat3, C2, C3);

  pack_qk_kernel<<<dim3(S / 2, H, 2 * BS), 192, 0, stream>>>(
      C3, C3 + UP, C2, C1 + 2 * DOWN, ct, st, Qp, Kp);
  transpose_kernel<<<dim3(M / 64, UP / 64), 256, 0, stream>>>(
      C2 + UP, N2, Vt, M);

  // barrier-free split-K attention: 2048 blocks x 4 waves (16q x 2 splits)
  attn_mfma<<<dim3(2048), 256, 0, stream>>>(Qp, Kp, Vt, attnb);

  // G4: out = attn @ Wfc^T  (BN=64 -> 1024 blocks)
  gemm_bt_mfma<64, float><<<dim3(M / 128, D / 64), 256, 0, stream>>>(
      attnb, UP, Wfcb, UP, bfc, out, D, UP);
}